// Round 3
// baseline (3353.585 us; speedup 1.0000x reference)
//
#include <hip/hip_runtime.h>

// ---------- problem constants ----------
// V=50000, E=300, H=512, BS=64, NSEG=3, SLEN=256 -> B3=192
// NNODE=18, NFEAT=600, NHID=600, NOUT=1024

typedef unsigned short ushort_t;
typedef __attribute__((ext_vector_type(8))) short bf16x8;   // 8 bf16 = 4 VGPRs
typedef __attribute__((ext_vector_type(4))) float f32x4;
typedef __attribute__((ext_vector_type(4))) unsigned int u32x4;

// output element offsets (fp32 elements)
#define OUT_RFTS 0UL
#define OUT_EMBS 25165824UL          // 64*768*512
#define OUT_MSKS 39911424UL          // + 64*768*300
#define OUT_SG   39960576UL          // + 64*768
#define OUT_HIDS 41140224UL          // + 64*18*1024

// workspace byte offsets
#define WS_HX   0UL                  // hx: 2*192*512 bf16 = 393,216 B
#define WS_FLG  393216UL             // flags: 96 x 128B lines

__device__ __forceinline__ ushort_t f2b(float f) {
  unsigned int u = __float_as_uint(f);
  u += 0x7fffu + ((u >> 16) & 1u);          // RNE
  return (ushort_t)(u >> 16);
}

union FRAG { ushort_t s[8]; bf16x8 v; uint2 u2[2]; };

__device__ __forceinline__ bf16x8 frag_from_f32(const float* p, bool v0, bool v1) {
  float4 a = v0 ? *(const float4*)p       : make_float4(0.f, 0.f, 0.f, 0.f);
  float4 b = v1 ? *(const float4*)(p + 4) : make_float4(0.f, 0.f, 0.f, 0.f);
  FRAG u;
  u.s[0] = f2b(a.x); u.s[1] = f2b(a.y); u.s[2] = f2b(a.z); u.s[3] = f2b(a.w);
  u.s[4] = f2b(b.x); u.s[5] = f2b(b.y); u.s[6] = f2b(b.z); u.s[7] = f2b(b.w);
  return u.v;
}

// ---- MALL-coherent helpers (bypass L1+L2 on the non-coherent XCDs) ----
__device__ __forceinline__ void st_mall_u32(void* a, unsigned int v) {
  asm volatile("global_store_dword %0, %1, off sc0 sc1" :: "v"(a), "v"(v) : "memory");
}
__device__ __forceinline__ void ld4x16_mall(
    const char* a0, const char* a1, const char* a2, const char* a3,
    u32x4& v0, u32x4& v1, u32x4& v2, u32x4& v3) {
  asm volatile(
      "global_load_dwordx4 %0, %4, off sc0 sc1\n\t"
      "global_load_dwordx4 %1, %5, off sc0 sc1\n\t"
      "global_load_dwordx4 %2, %6, off sc0 sc1\n\t"
      "global_load_dwordx4 %3, %7, off sc0 sc1\n\t"
      "s_waitcnt vmcnt(0)"
      : "=&v"(v0), "=&v"(v1), "=&v"(v2), "=&v"(v3)
      : "v"(a0), "v"(a1), "v"(a2), "v"(a3) : "memory");
}

// =====================================================================
// ONE dispatch, 256 blocks, 1 block/CU:
//   bid   0..47 : GRU, TWO groups per block (slice p of groups 2q, 2q+1).
//                 Weights depend only on (p,j) -> shared across both groups
//                 (zero extra register cost). Interleaving A/B steps hides
//                 the MALL publish->detect round trip under the other
//                 group's compute.
//   bid  48..111: GCN, one block per sample b.
//   bid 112..255: pack out_embs / out_msks / rfts tail zeros (144 blocks).
//
// Sync protocol = round-1-proven: flags via relaxed agent atomics (poll,
// publish), h payload via explicit sc0 sc1 asm ops (MALL-coherent).
// NO acquire fence: read-only data (emb/inds/weights) can't be stale, so
// L2 stays warm -> the 494MB/step-loop emb refetch disappears.
// Flag lines are touched ONLY by the atomic publishes (no plain stores in
// those lines -> no dirty-line writeback clobber; r2's bug).
// =====================================================================
__global__ __launch_bounds__(256, 1) void fused_all(
    const int* __restrict__ inds, const int* __restrict__ lens,
    const float* __restrict__ emb, const float* __restrict__ w_ih,
    const float* __restrict__ w_hh, const float* __restrict__ b_ih,
    const float* __restrict__ b_hh,
    const float* __restrict__ sgx, const float* __restrict__ adj,
    const float* __restrict__ gw1, const float* __restrict__ gb1,
    const float* __restrict__ gw2, const float* __restrict__ gb2,
    ushort_t* __restrict__ hx, unsigned int* __restrict__ flags,
    float* __restrict__ out)
{
  __shared__ __attribute__((aligned(16))) char smem[92304];
  const int bid = blockIdx.x;
  const int tid = threadIdx.x;

  if (bid < 48) {
    // ================= GRU: slice p of groups gA=2*gp, gB=2*gp+1 ==========
    const int gp = bid >> 3;       // 0..5
    const int p  = bid & 7;        // gate-slice 0..7
    const int gA = gp * 2, gB = gp * 2 + 1;

    ushort_t* hstA = (ushort_t*)smem;                 // 16*520 = 16640 B
    ushort_t* hstB = (ushort_t*)(smem + 16640);
    ushort_t* tokA = (ushort_t*)(smem + 33280);       // [2][16*328] = 20992 B
    ushort_t* tokB = (ushort_t*)(smem + 54272);
    int* sidxA = (int*)(smem + 75264);                // 16 ints
    int* sidxB = (int*)(smem + 75328);

    const int w = tid >> 6;
    const int l = tid & 63;
    const int jc = l & 15;
    const int quad = l >> 4;
    const int jg = p * 64 + w * 16 + jc;
    const int flA = (gA * 8 + p) * 32;
    const int flB = (gB * 8 + p) * 32;

    // ---- register/AGPR-resident w_hh slice ----
    bf16x8 bwh[3][16];
#pragma unroll
    for (int g3 = 0; g3 < 3; ++g3) {
      const float* wr = w_hh + (size_t)(g3 * 512 + jg) * 512 + quad * 8;
#pragma unroll
      for (int kc = 0; kc < 16; ++kc)
        bwh[g3][kc] = frag_from_f32(wr + kc * 32, true, true);
    }
    // ---- register-resident w_ih slice (K=300 padded to 320) ----
    bf16x8 bwx[3][10];
#pragma unroll
    for (int g3 = 0; g3 < 3; ++g3) {
      const float* wr = w_ih + (size_t)(g3 * 512 + jg) * 300;
#pragma unroll
      for (int kc = 0; kc < 10; ++kc) {
        const int k0 = kc * 32 + quad * 8;
        bwx[g3][kc] = frag_from_f32(wr + k0, k0 + 3 < 300, k0 + 7 < 300);
      }
    }
    const float bsr = b_ih[jg] + b_hh[jg];
    const float bsz = b_ih[512 + jg] + b_hh[512 + jg];
    const float bin = b_ih[1024 + jg];
    const float bhn = b_hh[1024 + jg];

    int TgA = 0, TgB = 0;
    for (int i = 0; i < 16; ++i) {
      TgA = max(TgA, lens[gA * 16 + i]);
      TgB = max(TgB, lens[gB * 16 + i]);
    }

    int lenA[4], lenB[4];
    unsigned int rfA[4], rfB[4], hxoA[4], hxoB[4], hidA[4], hidB[4];
    float hA[4] = {0.f, 0.f, 0.f, 0.f};
    float hB[4] = {0.f, 0.f, 0.f, 0.f};

    auto setup = [&](int g, int* len_q, unsigned int* rf_q,
                     unsigned int* hxo_q, unsigned int* hid_q) {
#pragma unroll
      for (int q = 0; q < 4; ++q) {
        int sl = quad * 4 + q;
        int b3 = g * 16 + sl;
        len_q[q] = lens[b3];
        int b = b3 / 3, seg = b3 - b * 3;
        int off = 0;
        for (int ss = 0; ss < seg; ++ss) off += lens[b * 3 + ss];
        rf_q[q]  = (unsigned int)(((unsigned)b * 768u + (unsigned)off) * 512u + (unsigned)jg);
        hxo_q[q] = (unsigned int)(b3 * 512 + (jg & ~1));
        hid_q[q] = (unsigned int)(OUT_HIDS + (size_t)b3 * 512 + jg);
      }
    };
    setup(gA, lenA, rfA, hxoA, hidA);
    setup(gB, lenB, rfB, hxoB, hidB);

    int trow[5], tcu[5];
#pragma unroll
    for (int c = 0; c < 5; ++c) {
      int u = c * 256 + tid;
      trow[c] = u / 80;
      tcu[c]  = u - trow[c] * 80;
    }

    // ---- prologue: stage tok(t=0) for both groups ----
    if (tid < 16) {
      sidxA[tid] = inds[(size_t)(gA * 16 + tid) * 256 + 0];
      sidxB[tid] = inds[(size_t)(gB * 16 + tid) * 256 + 0];
    }
    __syncthreads();
#pragma unroll
    for (int c = 0; c < 5; ++c) {
      float4 va = make_float4(0.f, 0.f, 0.f, 0.f);
      float4 vb = make_float4(0.f, 0.f, 0.f, 0.f);
      if (tcu[c] < 75) {
        va = *(const float4*)(emb + (size_t)sidxA[trow[c]] * 300 + tcu[c] * 4);
        vb = *(const float4*)(emb + (size_t)sidxB[trow[c]] * 300 + tcu[c] * 4);
      }
      FRAG ua, ub;
      ua.s[0] = f2b(va.x); ua.s[1] = f2b(va.y); ua.s[2] = f2b(va.z); ua.s[3] = f2b(va.w);
      ub.s[0] = f2b(vb.x); ub.s[1] = f2b(vb.y); ub.s[2] = f2b(vb.z); ub.s[3] = f2b(vb.w);
      *(uint2*)(&tokA[trow[c] * 328 + tcu[c] * 4]) = ua.u2[0];
      *(uint2*)(&tokB[trow[c] * 328 + tcu[c] * 4]) = ub.u2[0];
    }
    __syncthreads();

    const int HXE = 192 * 512;
    const f32x4 z4 = {0.f, 0.f, 0.f, 0.f};

    // ---- one GRU step for one group (fully inlined twice per iteration) --
    auto gstep = [&](int g, int fl, int t, int buf, int nbuf,
                     ushort_t* hst, ushort_t* tokbase, int* sidx,
                     float* h_q, int* len_q, unsigned int* rf_q,
                     unsigned int* hxo_q) {
      // per-wave poll (divergence makes the whole wave wait)
      if (l < 8) {
        const unsigned int* fa = &flags[(g * 8 + l) * 32];
        long guard = 0;
        while (__hip_atomic_load(fa, __ATOMIC_RELAXED, __HIP_MEMORY_SCOPE_AGENT)
               < (unsigned int)t) {
          __builtin_amdgcn_s_sleep(1);
          if (++guard > 5000000L) break;
        }
      }
      if (tid < 16) {
        int tt = (t + 1 < 256) ? t + 1 : 255;
        sidx[tid] = inds[(size_t)(g * 16 + tid) * 256 + tt];
      }
      // stage h: coalesced MALL loads (4 x 16B per thread, one waitcnt)
      {
        const char* hsrc = (const char*)(hx + (size_t)buf * HXE + (size_t)g * 16 * 512);
        u32x4 v0, v1, v2, v3;
        ld4x16_mall(hsrc + (size_t)(0 * 256 + tid) * 16,
                    hsrc + (size_t)(1 * 256 + tid) * 16,
                    hsrc + (size_t)(2 * 256 + tid) * 16,
                    hsrc + (size_t)(3 * 256 + tid) * 16,
                    v0, v1, v2, v3);
        const int i0 = tid, i1 = 256 + tid, i2 = 512 + tid, i3 = 768 + tid;
        *(u32x4*)(&hst[(i0 >> 6) * 520 + (i0 & 63) * 8]) = v0;
        *(u32x4*)(&hst[(i1 >> 6) * 520 + (i1 & 63) * 8]) = v1;
        *(u32x4*)(&hst[(i2 >> 6) * 520 + (i2 & 63) * 8]) = v2;
        *(u32x4*)(&hst[(i3 >> 6) * 520 + (i3 & 63) * 8]) = v3;
      }
      __syncthreads();                 // hst + sidx ready for all waves
      // tok prefetch for t+1 (plain loads; emb is read-only -> L2 hits now)
      float4 tr[5];
#pragma unroll
      for (int c = 0; c < 5; ++c) {
        tr[c] = make_float4(0.f, 0.f, 0.f, 0.f);
        if (tcu[c] < 75)
          tr[c] = *(const float4*)(emb + (size_t)sidx[trow[c]] * 300 + tcu[c] * 4);
      }
      // MFMA phase
      f32x4 accr = z4, accz = z4, anh = z4, anx = z4;
      const ushort_t* tokc = tokbase + buf * (16 * 328);
#pragma unroll
      for (int kc = 0; kc < 16; ++kc) {
        bf16x8 af = *(const bf16x8*)(&hst[(l & 15) * 520 + kc * 32 + quad * 8]);
        accr = __builtin_amdgcn_mfma_f32_16x16x32_bf16(af, bwh[0][kc], accr, 0, 0, 0);
        accz = __builtin_amdgcn_mfma_f32_16x16x32_bf16(af, bwh[1][kc], accz, 0, 0, 0);
        anh  = __builtin_amdgcn_mfma_f32_16x16x32_bf16(af, bwh[2][kc], anh, 0, 0, 0);
      }
#pragma unroll
      for (int kc = 0; kc < 10; ++kc) {
        bf16x8 xf = *(const bf16x8*)(&tokc[(l & 15) * 328 + kc * 32 + quad * 8]);
        accr = __builtin_amdgcn_mfma_f32_16x16x32_bf16(xf, bwx[0][kc], accr, 0, 0, 0);
        accz = __builtin_amdgcn_mfma_f32_16x16x32_bf16(xf, bwx[1][kc], accz, 0, 0, 0);
        anx  = __builtin_amdgcn_mfma_f32_16x16x32_bf16(xf, bwx[2][kc], anx, 0, 0, 0);
      }
      // gate math + h publish (critical path first)
      ushort_t* hxout = hx + (size_t)nbuf * HXE;
#pragma unroll
      for (int q = 0; q < 4; ++q) {
        float pr = accr[q] + bsr;
        float pz = accz[q] + bsz;
        float r = 1.f / (1.f + __expf(-pr));
        float z = 1.f / (1.f + __expf(-pz));
        float e2 = __expf(2.f * (anx[q] + bin + r * (anh[q] + bhn)));
        float n = 1.f - 2.f / (e2 + 1.f);          // tanh
        float hn = (1.f - z) * n + z * h_q[q];
        hn = (t < len_q[q]) ? hn : h_q[q];
        h_q[q] = hn;
        unsigned int hb = f2b(hn);
        unsigned int ob = (unsigned int)__shfl_xor((int)hb, 1, 64) & 0xffffu;
        if ((jc & 1) == 0) {
          unsigned int pv = (hb & 0xffffu) | (ob << 16);
          st_mall_u32((void*)(hxout + hxo_q[q]), pv);
        }
      }
      asm volatile("s_waitcnt vmcnt(0)" ::: "memory");  // h stores acked at MALL
      __syncthreads();
      if (tid == 0)
        __hip_atomic_store(&flags[fl], (unsigned int)(t + 1),
                           __ATOMIC_RELAXED, __HIP_MEMORY_SCOPE_AGENT);
      // off the critical chain: rfts fp32 stores + tok commit for t+1
#pragma unroll
      for (int q = 0; q < 4; ++q)
        if (t < len_q[q]) out[(size_t)rf_q[q] + (size_t)t * 512] = h_q[q];
      ushort_t* tokn = tokbase + nbuf * (16 * 328);
#pragma unroll
      for (int c = 0; c < 5; ++c) {
        FRAG u;
        u.s[0] = f2b(tr[c].x); u.s[1] = f2b(tr[c].y);
        u.s[2] = f2b(tr[c].z); u.s[3] = f2b(tr[c].w);
        *(uint2*)(&tokn[trow[c] * 328 + tcu[c] * 4]) = u.u2[0];
      }
      // (next iteration's pre-MFMA barrier orders these LDS writes)
    };

    const int Tmax = max(TgA, TgB);
    for (int t = 0; t < Tmax; ++t) {
      const int buf = t & 1, nbuf = buf ^ 1;
      if (t < TgA) gstep(gA, flA, t, buf, nbuf, hstA, tokA, sidxA, hA, lenA, rfA, hxoA);
      if (t < TgB) gstep(gB, flB, t, buf, nbuf, hstB, tokB, sidxB, hB, lenB, rfB, hxoB);
    }
#pragma unroll
    for (int q = 0; q < 4; ++q) {
      out[hidA[q]] = hA[q];
      out[hidB[q]] = hB[q];
    }

  } else if (bid < 112) {
    // ================= GCN: one block per sample ================
    const int b = bid - 48;
    float* xs   = (float*)smem;            // 18*600
    float* h1s  = (float*)smem + 10800;    // 18*600
    float* adjs = (float*)smem + 21600;    // 324
    float* ts   = (float*)smem + 21924;    // 1152

    for (int i = tid; i < 18 * 600; i += 256) xs[i] = sgx[(size_t)b * 10800 + i];
    for (int i = tid; i < 324; i += 256) adjs[i] = adj[(size_t)b * 324 + i];
    __syncthreads();

    for (int cb = 0; cb < 10; ++cb) {
      const int c0 = cb * 64;
      for (int o = tid; o < 1152; o += 256) {
        const int r = o >> 6, c = c0 + (o & 63);
        float a0 = 0.f, a1 = 0.f;
        if (c < 600) {
          const float* xr = xs + r * 600;
          for (int k = 0; k < 600; k += 2) {
            a0 += xr[k]     * gw1[(size_t)k * 600 + c];
            a1 += xr[k + 1] * gw1[(size_t)(k + 1) * 600 + c];
          }
        }
        ts[o] = a0 + a1;
      }
      __syncthreads();
      for (int o = tid; o < 1152; o += 256) {
        const int n = o >> 6, cl = o & 63, c = c0 + cl;
        if (c < 600) {
          float acc = gb1[c];
#pragma unroll
          for (int m = 0; m < 18; ++m) acc += adjs[n * 18 + m] * ts[m * 64 + cl];
          h1s[n * 600 + c] = fmaxf(acc, 0.f);
        }
      }
      __syncthreads();
    }
    for (int cb = 0; cb < 16; ++cb) {
      const int c0 = cb * 64;
      for (int o = tid; o < 1152; o += 256) {
        const int r = o >> 6, c = c0 + (o & 63);
        const float* xr = h1s + r * 600;
        float a0 = 0.f, a1 = 0.f;
        for (int k = 0; k < 600; k += 2) {
          a0 += xr[k]     * gw2[(size_t)k * 1024 + c];
          a1 += xr[k + 1] * gw2[(size_t)(k + 1) * 1024 + c];
        }
        ts[o] = a0 + a1;
      }
      __syncthreads();
      for (int o = tid; o < 1152; o += 256) {
        const int n = o >> 6, cl = o & 63, c = c0 + cl;
        float acc = gb2[c];
#pragma unroll
        for (int m = 0; m < 18; ++m) acc += adjs[n * 18 + m] * ts[m * 64 + cl];
        out[OUT_SG + (size_t)b * 18432 + n * 1024 + c] = acc;
      }
      __syncthreads();
    }

  } else {
    // ================= pack: out_embs + out_msks + rfts tail zeros =========
    // 144 blocks x 4 waves = 576 waves over 64*768 = 49152 (b,p) pairs.
    const int wid = (bid - 112) * 4 + (tid >> 6);   // 0..575
    const int l = tid & 63;
    for (int pr = wid; pr < 49152; pr += 576) {
      const int b = pr / 768;
      const int pp = pr - b * 768;
      const int l0 = lens[b * 3], l1 = lens[b * 3 + 1], l2v = lens[b * 3 + 2];
      const int tlen = l0 + l1 + l2v;
      if (l == 0)
        out[OUT_MSKS + (size_t)b * 768 + pp] = (pp < tlen) ? 1.0f : 0.0f;
      const size_t rfoff = OUT_RFTS + ((size_t)b * 768 + pp) * 512;
      const size_t eboff = OUT_EMBS + ((size_t)b * 768 + pp) * 300;
      if (pp >= tlen) {
        const float4 zz = make_float4(0.f, 0.f, 0.f, 0.f);
        *(float4*)(out + rfoff + (size_t)l * 8)     = zz;
        *(float4*)(out + rfoff + (size_t)l * 8 + 4) = zz;
        for (int u = l; u < 75; u += 64)
          *(float4*)(out + eboff + (size_t)u * 4) = zz;
      } else {
        int sgi, tt;
        if (pp < l0)           { sgi = 0; tt = pp; }
        else if (pp < l0 + l1) { sgi = 1; tt = pp - l0; }
        else                   { sgi = 2; tt = pp - l0 - l1; }
        const int ind = inds[(b * 3 + sgi) * 256 + tt];
        const float* src = emb + (size_t)ind * 300;
        for (int u = l; u < 75; u += 64)
          *(float4*)(out + eboff + (size_t)u * 4) = *(const float4*)(src + (size_t)u * 4);
      }
    }
  }
}

// =====================================================================
extern "C" void kernel_launch(void* const* d_in, const int* in_sizes, int n_in,
                              void* d_out, int out_size, void* d_ws, size_t ws_size,
                              hipStream_t stream)
{
  (void)in_sizes; (void)n_in; (void)out_size; (void)ws_size;
  const int*   inds = (const int*)d_in[0];
  const int*   lens = (const int*)d_in[1];
  const float* emb  = (const float*)d_in[2];
  const float* w_ih = (const float*)d_in[3];
  const float* w_hh = (const float*)d_in[4];
  const float* b_ih = (const float*)d_in[5];
  const float* b_hh = (const float*)d_in[6];
  const float* sgx  = (const float*)d_in[7];
  const float* adj  = (const float*)d_in[8];
  const float* gw1  = (const float*)d_in[9];
  const float* gb1  = (const float*)d_in[10];
  const float* gw2  = (const float*)d_in[11];
  const float* gb2  = (const float*)d_in[12];
  float* out = (float*)d_out;
  char* ws = (char*)d_ws;
  ushort_t* hx = (ushort_t*)(ws + WS_HX);
  unsigned int* flags = (unsigned int*)(ws + WS_FLG);

  // zero h0 double-buffer + flags (memset kernel's end-of-kernel writeback
  // makes the zeros MALL-visible before fused_all starts)
  hipMemsetAsync(ws, 0, 405504, stream);
  fused_all<<<dim3(256), 256, 0, stream>>>(inds, lens, emb, w_ih, w_hh, b_ih, b_hh,
                                           sgx, adj, gw1, gb1, gw2, gb2,
                                           hx, flags, out);
}